// Round 4
// baseline (75.414 us; speedup 1.0000x reference)
//
#include <hip/hip_runtime.h>
#include <hip/hip_bf16.h>

#define NROWS 8192
#define DIM 64
#define NT 64                     // 64x64 grid of 128x128 tiles
#define NTRI (NT * (NT + 1) / 2)  // 2080 upper-triangle tiles
#define TPB 2                     // tiles per block
#define NBLK (NTRI / TPB)         // 1040 blocks

typedef __attribute__((ext_vector_type(8))) short short8;   // 8 bf16 = 4 VGPRs
typedef __attribute__((ext_vector_type(4))) float f32x4;    // MFMA 16x16 accumulator

static constexpr float LOG2E = 1.4426950408889634f;

#if defined(__has_builtin) && __has_builtin(__builtin_amdgcn_exp2f)
#define EXP2F(x) __builtin_amdgcn_exp2f(x)
#else
#define EXP2F(x) exp2f(x)
#endif

// Panelized bf16 layout: panel p = row/16 holds rows 16p..16p+15.
// Within a panel, 8 k-chunks (c = k/8), stored chunk-major in 16B units:
//   unit_index = p*128 + c*16 + (row%16)
// An MFMA A/B fragment load (lane l16 = row%16, quad = (k/8)%4) is then a
// fully-coalesced contiguous 1KB wave load — no cache-line splits.
__global__ __launch_bounds__(256) void prep_kernel(const float* __restrict__ X,
                                                   const float* __restrict__ params,
                                                   float* __restrict__ Lsq,
                                                   short* __restrict__ Xp) {
    int tid  = threadIdx.x;
    int wave = tid >> 6, lane = tid & 63;
    int r8 = lane >> 3, c = lane & 7;        // 8 rows x 8 chunks per wave
    int row = blockIdx.x * 32 + wave * 8 + r8;

    const float* xr = X + row * DIM + c * 8;
    float4 x0 = *(const float4*)xr;
    float4 x1 = *(const float4*)(xr + 4);
    float4 p0 = *(const float4*)(params + c * 8);
    float4 p1 = *(const float4*)(params + c * 8 + 4);

    float v[8];
    v[0] = x0.x * sqrtf(p0.x); v[1] = x0.y * sqrtf(p0.y);
    v[2] = x0.z * sqrtf(p0.z); v[3] = x0.w * sqrtf(p0.w);
    v[4] = x1.x * sqrtf(p1.x); v[5] = x1.y * sqrtf(p1.y);
    v[6] = x1.z * sqrtf(p1.z); v[7] = x1.w * sqrtf(p1.w);

    short8 h;
    float s = 0.f;
    #pragma unroll
    for (int i = 0; i < 8; ++i) {
        __hip_bfloat16 b = __float2bfloat16(v[i]);
        union { __hip_bfloat16 bb; short ss; } u; u.bb = b;
        h[i] = u.ss;
        float bf = __bfloat162float(b);   // rounded value, consistent with MFMA dot
        s += bf * bf;
    }

    int panel = row >> 4, pr = row & 15;
    ((short8*)Xp)[panel * 128 + c * 16 + pr] = h;

    // sum s over the 8 chunk-lanes of this row (xor over lane bits 0..2)
    #pragma unroll
    for (int m = 1; m < 8; m <<= 1) s += __shfl_xor(s, m, 64);
    if (c == 0) Lsq[row] = LOG2E * s;
}

// Main: each block processes TWO consecutive upper-triangle 128x128 tiles.
// Consecutive tiles share the tile-row `it` except at row crossings
// (63/1040 blocks), so A-fragments + row operands load once; tile-1's
// B-fragments + column operands are prefetched right after tile-0's MFMAs
// and their latency hides under tile-0's ~1000-cycle exp epilogue. This
// halves cold block-starts (the round-1/2 counters showed kta is ~75%
// latency stall, not pipe-bound). NO fused finalize: per-block device-scope
// fence+atomic cost +26 us in rounds 1-2.
__global__ __launch_bounds__(256, 2) void kta_main(const short* __restrict__ Xp,
                                                   const float* __restrict__ Lsq,
                                                   const float* __restrict__ t,
                                                   float2* __restrict__ partial) {
    int k0 = blockIdx.x * TPB;
    // decode triangular index: row it has tiles jt = it..NT-1; C(i)=i*(129-i)/2
    int it = (int)((129.0f - sqrtf(16641.0f - 8.0f * (float)k0)) * 0.5f);
    if (it > NT - 1) it = NT - 1;
    while ((it * (129 - it)) / 2 > k0) --it;
    while (((it + 1) * (128 - it)) / 2 <= k0) ++it;
    int jt = it + (k0 - (it * (129 - it)) / 2);

    int tid  = threadIdx.x;
    int wave = tid >> 6, lane = tid & 63;
    int quad = lane >> 4, l16 = lane & 15;
    int wr = (wave >> 1) * 64, wc = (wave & 1) * 64;

    const short8* Xpv = (const short8*)Xp;

    short8 afr[4][2], bfr[4][2];
    float LsqR[4][4], tR[4][4];
    float LsqC0[4], tC0[4], LsqC1[4], tC1[4];

    // ---- tile 0 operand loads (A, B, row ops, col ops) ----
    int rbase = it * 128 + wr;
    int cbase = jt * 128 + wc;
    int pA0 = rbase >> 4, pB0 = cbase >> 4;
    #pragma unroll
    for (int rt = 0; rt < 4; ++rt)
        #pragma unroll
        for (int kc = 0; kc < 2; ++kc) {
            afr[rt][kc] = Xpv[(pA0 + rt) * 128 + (kc * 4 + quad) * 16 + l16];
            bfr[rt][kc] = Xpv[(pB0 + rt) * 128 + (kc * 4 + quad) * 16 + l16];
        }
    #pragma unroll
    for (int rt = 0; rt < 4; ++rt)
        #pragma unroll
        for (int r = 0; r < 4; ++r) {
            int row = rbase + rt * 16 + quad * 4 + r;
            LsqR[rt][r] = Lsq[row];
            tR[rt][r]   = t[row];
        }
    #pragma unroll
    for (int ct = 0; ct < 4; ++ct) {
        int col = cbase + ct * 16 + l16;
        LsqC0[ct] = Lsq[col];
        tC0[ct]   = t[col];
    }

    f32x4 c[4][4];

    // ---- MFMA tile 0 ----
    #pragma unroll
    for (int rt = 0; rt < 4; ++rt)
        #pragma unroll
        for (int ct = 0; ct < 4; ++ct) {
            c[rt][ct] = (f32x4){0.f, 0.f, 0.f, 0.f};
            c[rt][ct] = __builtin_amdgcn_mfma_f32_16x16x32_bf16(afr[rt][0], bfr[ct][0], c[rt][ct], 0, 0, 0);
            c[rt][ct] = __builtin_amdgcn_mfma_f32_16x16x32_bf16(afr[rt][1], bfr[ct][1], c[rt][ct], 0, 0, 0);
        }

    // ---- next tile coords + prefetch (fast path: same tile-row) ----
    int it1 = it, jt1 = jt + 1;
    bool rowcross = (jt1 == NT);
    if (rowcross) { it1 = it + 1; jt1 = it1; }   // next tile is diagonal (it1,it1)
    int cbase1 = jt1 * 128 + wc;
    int pB1 = cbase1 >> 4;

    if (!rowcross) {
        // overwrite bfr (tile-0 MFMAs already consumed it): loads fly during
        // tile-0's epilogue, waitcnt lands just before tile-1's MFMAs.
        #pragma unroll
        for (int rt = 0; rt < 4; ++rt)
            #pragma unroll
            for (int kc = 0; kc < 2; ++kc)
                bfr[rt][kc] = Xpv[(pB1 + rt) * 128 + (kc * 4 + quad) * 16 + l16];
        #pragma unroll
        for (int ct = 0; ct < 4; ++ct) {
            int col = cbase1 + ct * 16 + l16;
            LsqC1[ct] = Lsq[col];
            tC1[ct]   = t[col];
        }
    }

    float s1 = 0.f, s2a = 0.f, s2b = 0.f;

    // Epilogue over one 64x64 accumulator quadrant. C/D layout:
    // col = lane&15, row = quad*4 + reg. DIAG is a call-site literal so the
    // non-diag instantiation carries zero diagonal-compare cost.
    auto epi = [&](const float (&LC)[4], const float (&TC)[4], bool dwave, float w) {
        float t1 = 0.f, t2a = 0.f, t2b = 0.f;
        auto body = [&](int DIAG) {
            #pragma unroll
            for (int rt = 0; rt < 4; ++rt) {
                #pragma unroll
                for (int r = 0; r < 4; ++r) {
                    float nr = LsqR[rt][r];
                    float s1row = 0.f;
                    #pragma unroll
                    for (int ct = 0; ct < 4; ++ct) {
                        float dot = c[rt][ct][r];
                        // off-diag d2 >= ~15 for this data: no clamp needed;
                        // diagonal (the only d2~0 entries) pinned to 1 below.
                        float K = EXP2F(fmaf(dot, 2.0f * LOG2E, -(nr + LC[ct])));
                        if (DIAG && (rt == ct) && ((quad * 4 + r) == l16))
                            K = 1.0f;
                        s1row = fmaf(K, TC[ct], s1row);
                        if (ct & 2) t2b = fmaf(K, K, t2b);
                        else        t2a = fmaf(K, K, t2a);
                    }
                    t1 = fmaf(s1row, tR[rt][r], t1);
                }
            }
        };
        if (dwave) body(1); else body(0);
        s1  = fmaf(t1,  w, s1);
        s2a = fmaf(t2a, w, s2a);
        s2b = fmaf(t2b, w, s2b);
    };

    // ---- epilogue tile 0 ----
    bool dw0 = (it == jt) && ((wave >> 1) == (wave & 1));
    epi(LsqC0, tC0, dw0, (it == jt) ? 1.0f : 2.0f);

    if (rowcross) {
        // slow path (63/1040 blocks): reload A/B/row/col operands for the
        // diagonal tile (it1,it1). A == B panels on the diagonal.
        int rbase1 = it1 * 128 + wr;
        int pA1 = rbase1 >> 4;
        #pragma unroll
        for (int rt = 0; rt < 4; ++rt)
            #pragma unroll
            for (int kc = 0; kc < 2; ++kc) {
                afr[rt][kc] = Xpv[(pA1 + rt) * 128 + (kc * 4 + quad) * 16 + l16];
                bfr[rt][kc] = Xpv[(pB1 + rt) * 128 + (kc * 4 + quad) * 16 + l16];
            }
        #pragma unroll
        for (int rt = 0; rt < 4; ++rt)
            #pragma unroll
            for (int r = 0; r < 4; ++r) {
                int row = rbase1 + rt * 16 + quad * 4 + r;
                LsqR[rt][r] = Lsq[row];
                tR[rt][r]   = t[row];
            }
        #pragma unroll
        for (int ct = 0; ct < 4; ++ct) {
            int col = cbase1 + ct * 16 + l16;
            LsqC1[ct] = Lsq[col];
            tC1[ct]   = t[col];
        }
    }

    // ---- MFMA tile 1 (afr unchanged on fast path = same tile-row) ----
    #pragma unroll
    for (int rt = 0; rt < 4; ++rt)
        #pragma unroll
        for (int ct = 0; ct < 4; ++ct) {
            c[rt][ct] = (f32x4){0.f, 0.f, 0.f, 0.f};
            c[rt][ct] = __builtin_amdgcn_mfma_f32_16x16x32_bf16(afr[rt][0], bfr[ct][0], c[rt][ct], 0, 0, 0);
            c[rt][ct] = __builtin_amdgcn_mfma_f32_16x16x32_bf16(afr[rt][1], bfr[ct][1], c[rt][ct], 0, 0, 0);
        }

    // ---- epilogue tile 1 ----
    // rowcross => diagonal tile (weight 1, diag pinning); else off-diag.
    bool dw1 = rowcross && ((wave >> 1) == (wave & 1));
    epi(LsqC1, tC1, dw1, rowcross ? 1.0f : 2.0f);

    float s2 = s2a + s2b;
    #pragma unroll
    for (int m = 32; m > 0; m >>= 1) {
        s1 += __shfl_xor(s1, m, 64);
        s2 += __shfl_xor(s2, m, 64);
    }

    __shared__ float2 red[4];
    if (lane == 0) red[wave] = make_float2(s1, s2);
    __syncthreads();
    if (tid == 0) {
        float2 a = red[0], b = red[1], cc = red[2], d = red[3];
        partial[blockIdx.x] = make_float2(a.x + b.x + cc.x + d.x, a.y + b.y + cc.y + d.y);
    }
}

// Single-block reduction of per-block partials (1040 float2 = 8.3 KB).
__global__ __launch_bounds__(256) void finalize_kernel(const float2* __restrict__ partial,
                                                       float* __restrict__ out) {
    float s1 = 0.f, s2 = 0.f;
    for (int i = threadIdx.x; i < NBLK; i += 256) {
        float2 p = partial[i];
        s1 += p.x;
        s2 += p.y;
    }
    #pragma unroll
    for (int m = 32; m > 0; m >>= 1) {
        s1 += __shfl_xor(s1, m, 64);
        s2 += __shfl_xor(s2, m, 64);
    }
    __shared__ float r1[4], r2[4];
    int wave = threadIdx.x >> 6, lane = threadIdx.x & 63;
    if (lane == 0) { r1[wave] = s1; r2[wave] = s2; }
    __syncthreads();
    if (threadIdx.x == 0) {
        float a = r1[0] + r1[1] + r1[2] + r1[3];
        float b = r2[0] + r2[1] + r2[2] + r2[3];
        out[0] = -a / ((float)NROWS * sqrtf(b));
    }
}

extern "C" void kernel_launch(void* const* d_in, const int* in_sizes, int n_in,
                              void* d_out, int out_size, void* d_ws, size_t ws_size,
                              hipStream_t stream) {
    const float* X      = (const float*)d_in[0];
    const float* target = (const float*)d_in[1];
    const float* params = (const float*)d_in[2];
    float* out = (float*)d_out;

    float* ws = (float*)d_ws;
    float2* partial = (float2*)ws;                 // 1040 float2 (8.3 KB)
    float* Lsq = ws + 8192;                        // 8192 floats (32 KB)
    short* Xp  = (short*)(ws + 16384);             // panelized bf16, 1 MB, 64KB-offset aligned

    prep_kernel<<<NROWS / 32, 256, 0, stream>>>(X, params, Lsq, Xp);
    kta_main<<<NBLK, 256, 0, stream>>>(Xp, Lsq, target, partial);
    finalize_kernel<<<1, 256, 0, stream>>>(partial, out);
}

// Round 5
// 74.885 us; speedup vs baseline: 1.0071x; 1.0071x over previous
//
#include <hip/hip_runtime.h>
#include <hip/hip_bf16.h>

#define NROWS 8192
#define DIM 64
#define NT 64                     // 64x64 grid of 128x128 tiles
#define NTRI (NT * (NT + 1) / 2)  // 2080 upper-triangle tiles

typedef __attribute__((ext_vector_type(8))) short short8;   // 8 bf16 = 4 VGPRs
typedef __attribute__((ext_vector_type(4))) float f32x4;    // MFMA 16x16 accumulator

static constexpr float LOG2E = 1.4426950408889634f;

#if defined(__has_builtin) && __has_builtin(__builtin_amdgcn_exp2f)
#define EXP2F(x) __builtin_amdgcn_exp2f(x)
#else
#define EXP2F(x) exp2f(x)
#endif

// Panelized bf16 layout: panel p = row/16 holds rows 16p..16p+15.
// Within a panel, 8 k-chunks (c = k/8), stored chunk-major in 16B units:
//   unit_index = p*128 + c*16 + (row%16)
// A 128-row tile = 8 consecutive panels = 16 KB contiguous — stageable to
// LDS with plain coalesced copies.
__global__ __launch_bounds__(256) void prep_kernel(const float* __restrict__ X,
                                                   const float* __restrict__ params,
                                                   float* __restrict__ Lsq,
                                                   short* __restrict__ Xp) {
    int tid  = threadIdx.x;
    int wave = tid >> 6, lane = tid & 63;
    int r8 = lane >> 3, c = lane & 7;        // 8 rows x 8 chunks per wave
    int row = blockIdx.x * 32 + wave * 8 + r8;

    const float* xr = X + row * DIM + c * 8;
    float4 x0 = *(const float4*)xr;
    float4 x1 = *(const float4*)(xr + 4);
    float4 p0 = *(const float4*)(params + c * 8);
    float4 p1 = *(const float4*)(params + c * 8 + 4);

    float v[8];
    v[0] = x0.x * sqrtf(p0.x); v[1] = x0.y * sqrtf(p0.y);
    v[2] = x0.z * sqrtf(p0.z); v[3] = x0.w * sqrtf(p0.w);
    v[4] = x1.x * sqrtf(p1.x); v[5] = x1.y * sqrtf(p1.y);
    v[6] = x1.z * sqrtf(p1.z); v[7] = x1.w * sqrtf(p1.w);

    short8 h;
    float s = 0.f;
    #pragma unroll
    for (int i = 0; i < 8; ++i) {
        __hip_bfloat16 b = __float2bfloat16(v[i]);
        union { __hip_bfloat16 bb; short ss; } u; u.bb = b;
        h[i] = u.ss;
        float bf = __bfloat162float(b);   // rounded value, consistent with MFMA dot
        s += bf * bf;
    }

    int panel = row >> 4, pr = row & 15;
    ((short8*)Xp)[panel * 128 + c * 16 + pr] = h;

    // sum s over the 8 chunk-lanes of this row (xor over lane bits 0..2)
    #pragma unroll
    for (int m = 1; m < 8; m <<= 1) s += __shfl_xor(s, m, 64);
    if (c == 0) Lsq[row] = LOG2E * s;
}

// Main: one 128x128 tile per block; A/B panels staged to LDS (16 KB each),
// B-fragments in regs, A-fragments + 4 accumulator tiles streamed per-rt
// with the exp epilogue fused per-rt. Low VGPR (~115) -> 3-4 waves/SIMD:
// rounds 0-4 showed kta is ~70% latency stall at 2 waves/SIMD, and round 1
// showed low-VGPR is only safe when remat hits LDS (cheap) instead of
// global (L2/L3 round-trip). NO fused finalize (rounds 1-2: per-block
// device-scope fence+atomic cost +26 us).
__global__ __launch_bounds__(256, 3) void kta_main(const short* __restrict__ Xp,
                                                   const float* __restrict__ Lsq,
                                                   const float* __restrict__ t,
                                                   float2* __restrict__ partial) {
    int k = blockIdx.x;
    // decode triangular index: row it has tiles jt = it..NT-1; C(i)=i*(129-i)/2
    int it = (int)((129.0f - sqrtf(16641.0f - 8.0f * (float)k)) * 0.5f);
    if (it > NT - 1) it = NT - 1;
    while ((it * (129 - it)) / 2 > k) --it;
    while (((it + 1) * (128 - it)) / 2 <= k) ++it;
    int jt = it + (k - (it * (129 - it)) / 2);

    int tid  = threadIdx.x;
    int wave = tid >> 6, lane = tid & 63;
    int quad = lane >> 4, l16 = lane & 15;

    __shared__ short8 As[1024];   // 8 panels x 128 units = 16 KB
    __shared__ short8 Bs[1024];   // 16 KB

    const short8* Xpv  = (const short8*)Xp;
    const short8* Asrc = Xpv + (size_t)it * 1024;   // tile-row panels, contiguous
    const short8* Bsrc = Xpv + (size_t)jt * 1024;

    // Cooperative stage: 256 threads x 16 B = 4 KB/pass, 4 passes each.
    // Coalesced global loads; compiler batches loads then ds_writes.
    #pragma unroll
    for (int i = 0; i < 4; ++i) {
        As[tid + i * 256] = Asrc[tid + i * 256];
        Bs[tid + i * 256] = Bsrc[tid + i * 256];
    }

    int rbase = it * 128 + (wave >> 1) * 64;
    int cbase = jt * 128 + (wave & 1) * 64;

    // Epilogue operands from global, issued before the barrier so their
    // latency hides under the staging drain.
    float LsqR[4][4], tR[4][4];
    #pragma unroll
    for (int rt = 0; rt < 4; ++rt)
        #pragma unroll
        for (int r = 0; r < 4; ++r) {
            int row = rbase + rt * 16 + quad * 4 + r;
            LsqR[rt][r] = Lsq[row];
            tR[rt][r]   = t[row];
        }
    float LsqC[4], tC[4];
    #pragma unroll
    for (int ct = 0; ct < 4; ++ct) {
        int col = cbase + ct * 16 + l16;
        LsqC[ct] = Lsq[col];
        tC[ct]   = t[col];
    }

    __syncthreads();

    int lpA = (wave >> 1) * 4;   // local A panel base for this wave
    int lpB = (wave & 1) * 4;

    // B-fragments fully in regs (32 VGPR), reused by all 4 rt iterations.
    short8 bfr[4][2];
    #pragma unroll
    for (int ct = 0; ct < 4; ++ct)
        #pragma unroll
        for (int kc = 0; kc < 2; ++kc)
            bfr[ct][kc] = Bs[(lpB + ct) * 128 + (kc * 4 + quad) * 16 + l16];

    bool diagwave = (it == jt) && ((wave >> 1) == (wave & 1));
    float s1 = 0.f, s2a = 0.f, s2b = 0.f;

    // Per-rt streaming: 2 ds_reads (A-frags) -> 8 MFMAs -> fused epilogue.
    // Only 4 acc tiles (16 VGPR) + 2 A-frags (8 VGPR) live at a time.
    // DIAG is a call-site literal; non-diag waves carry zero compare cost.
    auto body = [&](int DIAG) {
        #pragma unroll
        for (int rt = 0; rt < 4; ++rt) {
            short8 a0 = As[(lpA + rt) * 128 + quad * 16 + l16];
            short8 a1 = As[(lpA + rt) * 128 + (4 + quad) * 16 + l16];
            f32x4 cc[4];
            #pragma unroll
            for (int ct = 0; ct < 4; ++ct) {
                cc[ct] = (f32x4){0.f, 0.f, 0.f, 0.f};
                cc[ct] = __builtin_amdgcn_mfma_f32_16x16x32_bf16(a0, bfr[ct][0], cc[ct], 0, 0, 0);
                cc[ct] = __builtin_amdgcn_mfma_f32_16x16x32_bf16(a1, bfr[ct][1], cc[ct], 0, 0, 0);
            }
            // Epilogue. C/D layout: col = lane&15, row = quad*4 + reg.
            #pragma unroll
            for (int r = 0; r < 4; ++r) {
                float nr = LsqR[rt][r];
                float s1row = 0.f;
                #pragma unroll
                for (int ct = 0; ct < 4; ++ct) {
                    float dot = cc[ct][r];
                    // off-diag d2 >= ~15 for this data: no clamp needed;
                    // diagonal (the only d2~0 entries) pinned to 1 below.
                    float K = EXP2F(fmaf(dot, 2.0f * LOG2E, -(nr + LsqC[ct])));
                    if (DIAG && (rt == ct) && ((quad * 4 + r) == l16))
                        K = 1.0f;
                    s1row = fmaf(K, tC[ct], s1row);
                    if (ct & 2) s2b = fmaf(K, K, s2b);
                    else        s2a = fmaf(K, K, s2a);
                }
                s1 = fmaf(s1row, tR[rt][r], s1);
            }
        }
    };
    if (diagwave) body(1); else body(0);

    float s2 = s2a + s2b;
    float w = (it == jt) ? 1.0f : 2.0f;
    s1 *= w; s2 *= w;
    #pragma unroll
    for (int m = 32; m > 0; m >>= 1) {
        s1 += __shfl_xor(s1, m, 64);
        s2 += __shfl_xor(s2, m, 64);
    }

    __shared__ float2 red[4];
    if (lane == 0) red[wave] = make_float2(s1, s2);
    __syncthreads();
    if (tid == 0) {
        float2 a = red[0], b = red[1], cc = red[2], d = red[3];
        partial[k] = make_float2(a.x + b.x + cc.x + d.x, a.y + b.y + cc.y + d.y);
    }
}

// Single-block reduction of per-block partials (2080 float2 = 16.6 KB).
__global__ __launch_bounds__(256) void finalize_kernel(const float2* __restrict__ partial,
                                                       float* __restrict__ out) {
    float s1 = 0.f, s2 = 0.f;
    for (int i = threadIdx.x; i < NTRI; i += 256) {
        float2 p = partial[i];
        s1 += p.x;
        s2 += p.y;
    }
    #pragma unroll
    for (int m = 32; m > 0; m >>= 1) {
        s1 += __shfl_xor(s1, m, 64);
        s2 += __shfl_xor(s2, m, 64);
    }
    __shared__ float r1[4], r2[4];
    int wave = threadIdx.x >> 6, lane = threadIdx.x & 63;
    if (lane == 0) { r1[wave] = s1; r2[wave] = s2; }
    __syncthreads();
    if (threadIdx.x == 0) {
        float a = r1[0] + r1[1] + r1[2] + r1[3];
        float b = r2[0] + r2[1] + r2[2] + r2[3];
        out[0] = -a / ((float)NROWS * sqrtf(b));
    }
}

extern "C" void kernel_launch(void* const* d_in, const int* in_sizes, int n_in,
                              void* d_out, int out_size, void* d_ws, size_t ws_size,
                              hipStream_t stream) {
    const float* X      = (const float*)d_in[0];
    const float* target = (const float*)d_in[1];
    const float* params = (const float*)d_in[2];
    float* out = (float*)d_out;

    float* ws = (float*)d_ws;
    float2* partial = (float2*)ws;                 // 2080 float2 (16.6 KB)
    float* Lsq = ws + 8192;                        // 8192 floats (32 KB)
    short* Xp  = (short*)(ws + 16384);             // panelized bf16, 1 MB, 64KB-offset aligned

    prep_kernel<<<NROWS / 32, 256, 0, stream>>>(X, params, Lsq, Xp);
    kta_main<<<NTRI, 256, 0, stream>>>(Xp, Lsq, target, partial);
    finalize_kernel<<<1, 256, 0, stream>>>(partial, out);
}